// Round 1
// baseline (982.419 us; speedup 1.0000x reference)
//
#include <hip/hip_runtime.h>
#include <hip/hip_bf16.h>
#include <stdint.h>

#define CLAMPV 10.0f

typedef unsigned short u16;
typedef __attribute__((ext_vector_type(8))) short short8;
typedef __attribute__((ext_vector_type(4))) float f32x4;

// ---- constants for this problem ----
#define NROWS 16384
#define IDIM  2048
#define ODIM  2048
#define KTOT  8192   // IDIM * 4  (T1..T4; T0 folded into bias)
#define BM 128
#define BN 128
#define BK 64        // bf16 elements per K-step (128 bytes per row)

__device__ __forceinline__ u16 f2bf(float f) {
    uint32_t u = __float_as_uint(f);
    u += 0x7fffu + ((u >> 16) & 1u);   // RNE
    return (u16)(u >> 16);
}

__device__ __forceinline__ void gload_lds16(const void* g, void* l) {
    __builtin_amdgcn_global_load_lds(
        (const __attribute__((address_space(1))) void*)g,
        (__attribute__((address_space(3))) void*)l, 16, 0, 0);
}

// ---------------------------------------------------------------------------
// Kernel 1: pack coeffs [O][I][5] fp32 -> B [O][KTOT] bf16 (d=1..4), bias[O]=sum_i c0
// one block per output row o
// ---------------------------------------------------------------------------
__global__ __launch_bounds__(256)
void pack_coeffs(const float* __restrict__ coeffs, u16* __restrict__ B,
                 float* __restrict__ bias)
{
    __shared__ float srow[IDIM * 5];      // 40 KB
    __shared__ float wsum[4];
    const int o = blockIdx.x;
    const int tid = threadIdx.x;
    const float* rp = coeffs + (size_t)o * IDIM * 5;

    // coalesced float4 stage of the whole row (10240 floats)
    for (int k = tid; k < IDIM * 5 / 4; k += 256)
        ((float4*)srow)[k] = ((const float4*)rp)[k];
    __syncthreads();

    float s0 = 0.f;
    for (int i = tid; i < IDIM; i += 256) {
        const float* c = &srow[i * 5];   // dword stride 5: coprime with 32 banks
        s0 += c[0];
        ushort4 pk;
        pk.x = f2bf(c[1]); pk.y = f2bf(c[2]); pk.z = f2bf(c[3]); pk.w = f2bf(c[4]);
        *(ushort4*)&B[(size_t)o * KTOT + i * 4] = pk;
    }
    // block reduction of s0
    #pragma unroll
    for (int off = 32; off; off >>= 1) s0 += __shfl_down(s0, off);
    if ((tid & 63) == 0) wsum[tid >> 6] = s0;
    __syncthreads();
    if (tid == 0) bias[o] = wsum[0] + wsum[1] + wsum[2] + wsum[3];
}

// ---------------------------------------------------------------------------
// Kernel 2: x fp32 -> A [rows][KTOT] bf16 with A[n][i*4+d] = T_{d+1}(tanh(clip(x)))
// 2 input elements per thread: 8B load, 16B store, grid-stride
// ---------------------------------------------------------------------------
__global__ __launch_bounds__(256)
void cheb_pack(const float* __restrict__ x, u16* __restrict__ A, int npair)
{
    for (int idx = blockIdx.x * 256 + threadIdx.x; idx < npair;
         idx += gridDim.x * 256) {
        float2 xv = ((const float2*)x)[idx];
        float xs[2] = {xv.x, xv.y};
        uint4 out;
        uint32_t w[4];
        #pragma unroll
        for (int e = 0; e < 2; ++e) {
            float xc = fminf(fmaxf(xs[e], -CLAMPV), CLAMPV);
            float t  = tanhf(xc);
            float t2 = 2.f * t * t  - 1.f;   // |T_d| <= 1: clips are no-ops
            float t3 = 2.f * t * t2 - t;
            float t4 = 2.f * t * t3 - t2;
            w[e * 2 + 0] = (uint32_t)f2bf(t)  | ((uint32_t)f2bf(t2) << 16);
            w[e * 2 + 1] = (uint32_t)f2bf(t3) | ((uint32_t)f2bf(t4) << 16);
        }
        out.x = w[0]; out.y = w[1]; out.z = w[2]; out.w = w[3];
        ((uint4*)A)[idx] = out;
    }
}

// ---------------------------------------------------------------------------
// Kernel 3: C[row0+ : ][ODIM] = clip(A @ B^T + bias)
// 128x128 tile, BK=64, 4 waves (2x2), 16x16x32 bf16 MFMA, global_load_lds(16B)
// XOR swizzle (both sides): lds position holds logical kchunk ^ (row&7)
// ---------------------------------------------------------------------------
__global__ __launch_bounds__(256)
void gemm_bt(const u16* __restrict__ A,   // [Mchunk][KTOT]
             const u16* __restrict__ B,   // [ODIM][KTOT]
             const float* __restrict__ bias,
             float* __restrict__ C,       // [NROWS][ODIM]
             int row0)
{
    __shared__ u16 sA[BM * BK];   // 16 KB
    __shared__ u16 sB[BN * BK];   // 16 KB

    const int tid  = threadIdx.x;
    const int lane = tid & 63;
    const int wave = tid >> 6;
    const int wm = wave >> 1, wn = wave & 1;
    const int bm = blockIdx.y;
    const int bn = blockIdx.x;
    const int col0 = bn * BN;

    const size_t strideB = (size_t)KTOT * 2;   // bytes per row
    const char* Abase = (const char*)A + (size_t)bm * BM * strideB;
    const char* Bbase = (const char*)B + (size_t)col0 * strideB;

    // staging map: chunk q = j*256 + tid in [0,1024); row=q>>3, swizzled col
    int srow_[4], scol_[4];
    #pragma unroll
    for (int j = 0; j < 4; ++j) {
        int q = j * 256 + tid;
        srow_[j] = q >> 3;
        scol_[j] = ((q & 7) ^ ((q >> 3) & 7)) * 16;   // byte offset in row
    }

    f32x4 acc[4][4] = {};

    for (int kt = 0; kt < KTOT / BK; ++kt) {
        const size_t kb = (size_t)kt * (BK * 2);
        #pragma unroll
        for (int j = 0; j < 4; ++j) {
            int q = j * 256 + tid;
            gload_lds16(Abase + (size_t)srow_[j] * strideB + kb + scol_[j],
                        (char*)sA + q * 16);
        }
        #pragma unroll
        for (int j = 0; j < 4; ++j) {
            int q = j * 256 + tid;
            gload_lds16(Bbase + (size_t)srow_[j] * strideB + kb + scol_[j],
                        (char*)sB + q * 16);
        }
        __syncthreads();   // compiler emits vmcnt(0) drain before barrier

        #pragma unroll
        for (int ks = 0; ks < 2; ++ks) {
            short8 af[4], bfr[4];
            #pragma unroll
            for (int mt = 0; mt < 4; ++mt) {
                int r  = wm * 64 + mt * 16 + (lane & 15);
                int cb = (ks * 64 + (lane >> 4) * 16) ^ ((r & 7) << 4);
                af[mt] = *(const short8*)((const char*)sA + r * 128 + cb);
            }
            #pragma unroll
            for (int nt = 0; nt < 4; ++nt) {
                int r  = wn * 64 + nt * 16 + (lane & 15);
                int cb = (ks * 64 + (lane >> 4) * 16) ^ ((r & 7) << 4);
                bfr[nt] = *(const short8*)((const char*)sB + r * 128 + cb);
            }
            #pragma unroll
            for (int mt = 0; mt < 4; ++mt)
                #pragma unroll
                for (int nt = 0; nt < 4; ++nt)
                    acc[mt][nt] = __builtin_amdgcn_mfma_f32_16x16x32_bf16(
                        af[mt], bfr[nt], acc[mt][nt], 0, 0, 0);
        }
        __syncthreads();   // protect LDS before next stage
    }

    // epilogue: + bias, clip, store fp32
    float bia[4];
    #pragma unroll
    for (int nt = 0; nt < 4; ++nt)
        bia[nt] = bias[col0 + wn * 64 + nt * 16 + (lane & 15)];

    #pragma unroll
    for (int mt = 0; mt < 4; ++mt) {
        int rbase = row0 + bm * BM + wm * 64 + mt * 16 + (lane >> 4) * 4;
        #pragma unroll
        for (int nt = 0; nt < 4; ++nt) {
            int col = col0 + wn * 64 + nt * 16 + (lane & 15);
            #pragma unroll
            for (int r = 0; r < 4; ++r) {
                float v = acc[mt][nt][r] + bia[nt];
                v = fminf(fmaxf(v, -CLAMPV), CLAMPV);
                C[(size_t)(rbase + r) * ODIM + col] = v;
            }
        }
    }
}

// ---------------------------------------------------------------------------
extern "C" void kernel_launch(void* const* d_in, const int* in_sizes, int n_in,
                              void* d_out, int out_size, void* d_ws, size_t ws_size,
                              hipStream_t stream)
{
    const float* x      = (const float*)d_in[0];
    const float* coeffs = (const float*)d_in[1];
    float* out = (float*)d_out;

    char* ws = (char*)d_ws;
    const size_t bBytes    = (size_t)ODIM * KTOT * 2;   // 33,554,432
    const size_t biasBytes = 8192;
    u16*   Bp   = (u16*)ws;
    float* bias = (float*)(ws + bBytes);
    u16*   Ap   = (u16*)(ws + bBytes + biasBytes);

    size_t avail = (ws_size > bBytes + biasBytes) ? ws_size - bBytes - biasBytes : 0;
    int chunk = NROWS;
    while (chunk > BM && (size_t)chunk * KTOT * 2 > avail) chunk >>= 1;

    pack_coeffs<<<ODIM, 256, 0, stream>>>(coeffs, Bp, bias);

    for (int r0 = 0; r0 < NROWS; r0 += chunk) {
        int npair = chunk * IDIM / 2;
        cheb_pack<<<2048, 256, 0, stream>>>(x + (size_t)r0 * IDIM, Ap, npair);
        dim3 grid(ODIM / BN, chunk / BM);
        gemm_bt<<<grid, 256, 0, stream>>>(Ap, Bp, bias, out, r0);
    }
}

// Round 3
// 737.877 us; speedup vs baseline: 1.3314x; 1.3314x over previous
//
#include <hip/hip_runtime.h>
#include <hip/hip_bf16.h>
#include <stdint.h>

#define CLAMPV 10.0f

typedef unsigned short u16;
typedef __attribute__((ext_vector_type(8))) short short8;
typedef __attribute__((ext_vector_type(4))) float f32x4;

#define NROWS 16384
#define IDIM  2048
#define ODIM  2048
#define KTOT  8192            // IDIM*4 (T1..T4; T0 folded into bias)
#define BK    64              // bf16 per K-step (128 B/row)
#define NT    (KTOT / BK)     // 128 K-tiles
#define ROWB  (KTOT * 2)      // bytes per matrix row

__device__ __forceinline__ u16 f2bf(float f) {
    uint32_t u = __float_as_uint(f);
    u += 0x7fffu + ((u >> 16) & 1u);   // RNE
    return (u16)(u >> 16);
}

__device__ __forceinline__ void gload_lds16(const void* g, void* l) {
    __builtin_amdgcn_global_load_lds(
        (const __attribute__((address_space(1))) void*)g,
        (__attribute__((address_space(3))) void*)l, 16, 0, 0);
}

// ---------------------------------------------------------------------------
// pack_coeffs: one wave per output row o. B[o][i*4+d-1]=bf16(c_d), bias[o]=sum c_0
// ---------------------------------------------------------------------------
__global__ __launch_bounds__(256)
void pack_coeffs(const float* __restrict__ coeffs, u16* __restrict__ B,
                 float* __restrict__ bias)
{
    const int lane = threadIdx.x & 63;
    const int o = blockIdx.x * 4 + (threadIdx.x >> 6);
    const float* rp = coeffs + (size_t)o * IDIM * 5;
    float s0 = 0.f;
    for (int i = lane; i < IDIM; i += 64) {
        const float* c = rp + i * 5;     // 5 dword loads, union is dense
        s0 += c[0];
        ushort4 pk;
        pk.x = f2bf(c[1]); pk.y = f2bf(c[2]); pk.z = f2bf(c[3]); pk.w = f2bf(c[4]);
        *(ushort4*)&B[(size_t)o * KTOT + i * 4] = pk;
    }
    #pragma unroll
    for (int off = 32; off; off >>= 1) s0 += __shfl_down(s0, off);
    if (lane == 0) bias[o] = s0;
}

// ---------------------------------------------------------------------------
// cheb_pack: 4 x-values/thread; branch-free tanh via exp; 16B in / 32B out
// ---------------------------------------------------------------------------
__global__ __launch_bounds__(256)
void cheb_pack(const float* __restrict__ x, u16* __restrict__ A, int nquad)
{
    for (int idx = blockIdx.x * 256 + threadIdx.x; idx < nquad;
         idx += gridDim.x * 256) {
        float4 xv = ((const float4*)x)[idx];
        float xs[4] = {xv.x, xv.y, xv.z, xv.w};
        uint32_t w[8];
        #pragma unroll
        for (int e = 0; e < 4; ++e) {
            float xc = fminf(fmaxf(xs[e], -CLAMPV), CLAMPV);
            float ex = __expf(2.f * xc);
            float t  = (ex - 1.f) / (ex + 1.f);      // tanh, branch-free
            float t2 = fmaf(2.f * t, t,  -1.f);      // |T_d|<=1: clips no-op
            float t3 = fmaf(2.f * t, t2, -t);
            float t4 = fmaf(2.f * t, t3, -t2);
            w[e*2]   = (uint32_t)f2bf(t)  | ((uint32_t)f2bf(t2) << 16);
            w[e*2+1] = (uint32_t)f2bf(t3) | ((uint32_t)f2bf(t4) << 16);
        }
        uint4 o0; o0.x = w[0]; o0.y = w[1]; o0.z = w[2]; o0.w = w[3];
        uint4 o1; o1.x = w[4]; o1.y = w[5]; o1.z = w[6]; o1.w = w[7];
        ((uint4*)A)[idx * 2]     = o0;
        ((uint4*)A)[idx * 2 + 1] = o1;
    }
}

// ---------------------------------------------------------------------------
// gemm: 256x256 tile, BK=64, 8 waves (2Mx4N), 8-phase schedule, counted vmcnt.
// LDS 128 KiB: [buf][A/B][256][64] bf16, XOR-swizzled (chunk ^= row&7, both sides).
// Parts (staged per phase, lands >=1 phase after region freed):
//   p0 A-even rows {0-63,128-191}   read P1   staged at P2 (tile t+2)
//   p1 B-even rows {0-31 mod 64}    read P1   staged at P3 (tile t+2)
//   p2 B-odd  rows {32-63 mod 64}   read P2   staged at P4 (tile t+2)
//   p3 A-odd  rows {64-127,192-255} read P3   staged at P1 (tile t+1)
// vmcnt(6) once per K-tile (3 parts in flight) -- never 0 in steady state.
// ---------------------------------------------------------------------------
__global__ __launch_bounds__(512, 2)
void gemm_bt(const u16* __restrict__ A, const u16* __restrict__ B,
             const float* __restrict__ bias, float* __restrict__ C,
             int row0)
{
    __shared__ u16 lds[2][2][256][64];   // 131072 B

    const int tid  = threadIdx.x;
    const int lane = tid & 63;
    const int wid  = tid >> 6;
    const int wm   = wid >> 2;      // 0..1
    const int wn   = wid & 3;       // 0..3

    // XCD-aware swizzle (gridDim.x % 8 == 0)
    const int bid = blockIdx.x;
    const int cpx = gridDim.x >> 3;
    const int swz = (bid & 7) * cpx + (bid >> 3);
    const int bn = swz & 7;          // ODIM/256 = 8 col tiles, fastest
    const int bm = swz >> 3;

    const char* gA = (const char*)A + (size_t)bm * 256 * ROWB;
    const char* gB = (const char*)B + (size_t)bn * 256 * ROWB;

    // ---- staging maps (2 glds per part per thread) ----
    const int c  = tid & 7;          // 16B chunk within 128B row
    const int rA = tid >> 3;         // 0..63
    const int rB = rA & 31;
    const int hb = tid >> 8;         // 0..1
    const int rA0_0 = rA,           rA0_1 = 128 + rA;            // p0
    const int rA1_0 = 64 + rA,      rA1_1 = 192 + rA;            // p3
    const int rB0_0 = hb*64 + rB,   rB0_1 = 128 + hb*64 + rB;    // p1
    const int rB1_0 = rB0_0 + 32,   rB1_1 = rB0_1 + 32;          // p2
#define SOFF(r) ((r) * ROWB + (((c ^ ((r) & 7))) << 4))
#define DOFF(r) ((r) * 128 + (c << 4))
    const int soA0_0 = SOFF(rA0_0), doA0_0 = DOFF(rA0_0);
    const int soA0_1 = SOFF(rA0_1), doA0_1 = DOFF(rA0_1);
    const int soA1_0 = SOFF(rA1_0), doA1_0 = DOFF(rA1_0);
    const int soA1_1 = SOFF(rA1_1), doA1_1 = DOFF(rA1_1);
    const int soB0_0 = SOFF(rB0_0), doB0_0 = DOFF(rB0_0);
    const int soB0_1 = SOFF(rB0_1), doB0_1 = DOFF(rB0_1);
    const int soB1_0 = SOFF(rB1_0), doB1_0 = DOFF(rB1_0);
    const int soB1_1 = SOFF(rB1_1), doB1_1 = DOFF(rB1_1);
#undef SOFF
#undef DOFF

    char* lbase = (char*)&lds[0][0][0][0];
    auto ST = [&](const char* gb, char* lb, int tile,
                  int so0, int do0, int so1, int do1) {
        const int kb = tile * 128;
        gload_lds16(gb + kb + so0, lb + do0);
        gload_lds16(gb + kb + so1, lb + do1);
    };

    // ---- fragment-read addressing ----
    const int aBase = (wm * 128 + (lane & 15)) * 128;
    const int bBase = (wn * 64  + (lane & 15)) * 128;
    const int sw  = (lane & 7) << 4;
    const int cb0 = ( (lane & 0x30)      ) ^ sw;
    const int cb1 = ( (lane & 0x30) + 64 ) ^ sw;

    f32x4 acc[8][4] = {};
    short8 aF[4][2], bE[2][2], bO[2][2];

    // ---- prologue: tile0 p0-p3, tile1 p0-p2 (7 parts = 14 loads/wave) ----
    ST(gA, lbase,                 0, soA0_0, doA0_0, soA0_1, doA0_1);
    ST(gB, lbase + 32768,         0, soB0_0, doB0_0, soB0_1, doB0_1);
    ST(gB, lbase + 32768,         0, soB1_0, doB1_0, soB1_1, doB1_1);
    ST(gA, lbase,                 0, soA1_0, doA1_0, soA1_1, doA1_1);
    ST(gA, lbase + 65536,         1, soA0_0, doA0_0, soA0_1, doA0_1);
    ST(gB, lbase + 65536 + 32768, 1, soB0_0, doB0_0, soB0_1, doB0_1);
    ST(gB, lbase + 65536 + 32768, 1, soB1_0, doB1_0, soB1_1, doB1_1);
    asm volatile("s_waitcnt vmcnt(6)" ::: "memory");   // tile0 landed
    __builtin_amdgcn_s_barrier();

#define PHASE_SYNC()                                          \
    __builtin_amdgcn_s_barrier();                             \
    asm volatile("s_waitcnt lgkmcnt(0)" ::: "memory");        \
    __builtin_amdgcn_sched_barrier(0)

    for (int t = 0; t < NT; ++t) {
        char* sA  = lbase + (t & 1) * 65536;
        char* sB  = sA + 32768;
        char* sAo = lbase + ((t + 1) & 1) * 65536;

        // ---------------- P1: quad (mh0, nh0) ----------------
        #pragma unroll
        for (int m = 0; m < 4; ++m) {
            aF[m][0] = *(const short8*)(sA + aBase + m * 2048 + cb0);
            aF[m][1] = *(const short8*)(sA + aBase + m * 2048 + cb1);
        }
        #pragma unroll
        for (int n = 0; n < 2; ++n) {
            bE[n][0] = *(const short8*)(sB + bBase + n * 2048 + cb0);
            bE[n][1] = *(const short8*)(sB + bBase + n * 2048 + cb1);
        }
        if (t + 1 < NT) ST(gA, sAo, t + 1, soA1_0, doA1_0, soA1_1, doA1_1);
        PHASE_SYNC();
        __builtin_amdgcn_s_setprio(1);
        #pragma unroll
        for (int ks = 0; ks < 2; ++ks)
            #pragma unroll
            for (int m = 0; m < 4; ++m)
                #pragma unroll
                for (int n = 0; n < 2; ++n)
                    acc[m][n] = __builtin_amdgcn_mfma_f32_16x16x32_bf16(
                        aF[m][ks], bE[n][ks], acc[m][n], 0, 0, 0);
        __builtin_amdgcn_s_setprio(0);
        __builtin_amdgcn_s_barrier();

        // ---------------- P2: quad (mh0, nh1) ----------------
        #pragma unroll
        for (int n = 0; n < 2; ++n) {
            bO[n][0] = *(const short8*)(sB + bBase + (n + 2) * 2048 + cb0);
            bO[n][1] = *(const short8*)(sB + bBase + (n + 2) * 2048 + cb1);
        }
        if (t + 2 < NT) ST(gA, sA, t + 2, soA0_0, doA0_0, soA0_1, doA0_1);
        PHASE_SYNC();
        __builtin_amdgcn_s_setprio(1);
        #pragma unroll
        for (int ks = 0; ks < 2; ++ks)
            #pragma unroll
            for (int m = 0; m < 4; ++m)
                #pragma unroll
                for (int n = 0; n < 2; ++n)
                    acc[m][n + 2] = __builtin_amdgcn_mfma_f32_16x16x32_bf16(
                        aF[m][ks], bO[n][ks], acc[m][n + 2], 0, 0, 0);
        __builtin_amdgcn_s_setprio(0);
        __builtin_amdgcn_s_barrier();

        // ---------------- P3: quad (mh1, nh1) ----------------
        #pragma unroll
        for (int m = 0; m < 4; ++m) {
            aF[m][0] = *(const short8*)(sA + aBase + 8192 + m * 2048 + cb0);
            aF[m][1] = *(const short8*)(sA + aBase + 8192 + m * 2048 + cb1);
        }
        if (t + 2 < NT) ST(gB, sB, t + 2, soB0_0, doB0_0, soB0_1, doB0_1);
        PHASE_SYNC();
        __builtin_amdgcn_s_setprio(1);
        #pragma unroll
        for (int ks = 0; ks < 2; ++ks)
            #pragma unroll
            for (int m = 0; m < 4; ++m)
                #pragma unroll
                for (int n = 0; n < 2; ++n)
                    acc[m + 4][n + 2] = __builtin_amdgcn_mfma_f32_16x16x32_bf16(
                        aF[m][ks], bO[n][ks], acc[m + 4][n + 2], 0, 0, 0);
        __builtin_amdgcn_s_setprio(0);
        __builtin_amdgcn_s_barrier();

        // ---------------- P4: quad (mh1, nh0) ----------------
        if (t + 2 < NT) ST(gB, sB, t + 2, soB1_0, doB1_0, soB1_1, doB1_1);
        PHASE_SYNC();
        __builtin_amdgcn_s_setprio(1);
        #pragma unroll
        for (int ks = 0; ks < 2; ++ks)
            #pragma unroll
            for (int m = 0; m < 4; ++m)
                #pragma unroll
                for (int n = 0; n < 2; ++n)
                    acc[m + 4][n] = __builtin_amdgcn_mfma_f32_16x16x32_bf16(
                        aF[m][ks], bE[n][ks], acc[m + 4][n], 0, 0, 0);
        __builtin_amdgcn_s_setprio(0);
        if (t < NT - 2)       { asm volatile("s_waitcnt vmcnt(6)" ::: "memory"); }
        else if (t == NT - 2) { asm volatile("s_waitcnt vmcnt(0)" ::: "memory"); }
        __builtin_amdgcn_s_barrier();
    }
#undef PHASE_SYNC

    // ---- epilogue: + bias, clip, store fp32 ----
    float bia[4];
    #pragma unroll
    for (int n = 0; n < 4; ++n)
        bia[n] = bias[bn * 256 + wn * 64 + n * 16 + (lane & 15)];

    #pragma unroll
    for (int m = 0; m < 8; ++m) {
        const int rb = row0 + bm * 256 + wm * 128 + m * 16 + ((lane >> 4) << 2);
        #pragma unroll
        for (int n = 0; n < 4; ++n) {
            const int col = bn * 256 + wn * 64 + n * 16 + (lane & 15);
            #pragma unroll
            for (int r = 0; r < 4; ++r) {
                float v = acc[m][n][r] + bia[n];
                v = fminf(fmaxf(v, -CLAMPV), CLAMPV);
                C[(size_t)(rb + r) * ODIM + col] = v;
            }
        }
    }
}

// ---------------------------------------------------------------------------
extern "C" void kernel_launch(void* const* d_in, const int* in_sizes, int n_in,
                              void* d_out, int out_size, void* d_ws, size_t ws_size,
                              hipStream_t stream)
{
    const float* x      = (const float*)d_in[0];
    const float* coeffs = (const float*)d_in[1];
    float* out = (float*)d_out;

    char* ws = (char*)d_ws;
    const size_t bBytes    = (size_t)ODIM * KTOT * 2;   // 33.5 MB
    const size_t biasBytes = 8192;
    u16*   Bp   = (u16*)ws;
    float* bias = (float*)(ws + bBytes);
    u16*   Ap   = (u16*)(ws + bBytes + biasBytes);

    size_t avail = (ws_size > bBytes + biasBytes) ? ws_size - bBytes - biasBytes : 0;
    int chunk = NROWS;
    while (chunk > 256 && (size_t)chunk * KTOT * 2 > avail) chunk >>= 1;

    pack_coeffs<<<ODIM / 4, 256, 0, stream>>>(coeffs, Bp, bias);

    for (int r0 = 0; r0 < NROWS; r0 += chunk) {
        cheb_pack<<<2048, 256, 0, stream>>>(x + (size_t)r0 * IDIM, Ap,
                                            chunk * IDIM / 4);
        gemm_bt<<<(chunk / 256) * 8, 512, 0, stream>>>(Ap, Bp, bias, out, r0);
    }
}

// Round 4
// 515.264 us; speedup vs baseline: 1.9066x; 1.4320x over previous
//
#include <hip/hip_runtime.h>
#include <hip/hip_bf16.h>
#include <stdint.h>

#define CLAMPV 10.0f

typedef signed char i8;
typedef __attribute__((ext_vector_type(4))) int   i32x4;
typedef __attribute__((ext_vector_type(4))) int   int4v;

#define NROWS 16384
#define IDIM  2048
#define ODIM  2048
#define KTOT  8192            // IDIM*4 (T1..T4 as i8; T0 folded into bias)
#define BKE   128             // i8 elems per K-step = 128 B/row (same bytes as before)
#define NT    (KTOT / BKE)    // 64 K-tiles
#define ROWB  KTOT            // bytes per matrix row (i8)

__device__ __forceinline__ void gload_lds16(const void* g, void* l) {
    __builtin_amdgcn_global_load_lds(
        (const __attribute__((address_space(1))) void*)g,
        (__attribute__((address_space(3))) void*)l, 16, 0, 0);
}

__device__ __forceinline__ uint32_t pack4(float a, float b, float c, float d) {
    int q0 = (int)rintf(a), q1 = (int)rintf(b), q2 = (int)rintf(c), q3 = (int)rintf(d);
    return (uint32_t)(uint8_t)q0 | ((uint32_t)(uint8_t)q1 << 8) |
           ((uint32_t)(uint8_t)q2 << 16) | ((uint32_t)(uint8_t)q3 << 24);
}

// ---------------------------------------------------------------------------
// pack_coeffs: block per output row o. LDS-staged coalesced read.
//   bias[o] = sum_i c0;  scale[o] = rowmax(|c1..c4|)/127;
//   B[o][i*4+d-1] = rint(c_d * 127/rowmax)
// ---------------------------------------------------------------------------
__global__ __launch_bounds__(256)
void pack_coeffs(const float* __restrict__ coeffs, uint32_t* __restrict__ B,
                 float* __restrict__ bias, float* __restrict__ scale)
{
    __shared__ float srow[IDIM * 5];      // 40 KB
    __shared__ float red[8];
    const int o = blockIdx.x;
    const int tid = threadIdx.x;
    const float* rp = coeffs + (size_t)o * IDIM * 5;

    for (int k = tid; k < IDIM * 5 / 4; k += 256)
        ((float4*)srow)[k] = ((const float4*)rp)[k];
    __syncthreads();

    float s0 = 0.f, mx = 0.f;
    for (int i = tid; i < IDIM; i += 256) {
        const float* c = &srow[i * 5];   // stride-5 dwords: 2-way bank alias, free
        s0 += c[0];
        mx = fmaxf(mx, fmaxf(fmaxf(fabsf(c[1]), fabsf(c[2])),
                             fmaxf(fabsf(c[3]), fabsf(c[4]))));
    }
    #pragma unroll
    for (int off = 32; off; off >>= 1) {
        s0 += __shfl_down(s0, off);
        mx = fmaxf(mx, __shfl_down(mx, off));
    }
    if ((tid & 63) == 0) { red[tid >> 6] = s0; red[4 + (tid >> 6)] = mx; }
    __syncthreads();
    const float m  = fmaxf(fmaxf(red[4], red[5]), fmaxf(red[6], red[7]));
    const float rs = 127.f / m;
    if (tid == 0) {
        bias[o]  = red[0] + red[1] + red[2] + red[3];
        scale[o] = m * (1.f / 127.f);
    }
    for (int i = tid; i < IDIM; i += 256) {
        const float* c = &srow[i * 5];
        B[(size_t)o * IDIM + i] = pack4(c[1] * rs, c[2] * rs, c[3] * rs, c[4] * rs);
    }
}

// ---------------------------------------------------------------------------
// cheb_pack: x fp32 -> A i8, A[n][i*4+d] = rint(127*T_{d+1}(tanh(clip(x))))
// 4 elems/thread: 16B in, 16B out; rcp instead of fp-div.
// ---------------------------------------------------------------------------
__global__ __launch_bounds__(256)
void cheb_pack(const float* __restrict__ x, uint32_t* __restrict__ A, int nquad)
{
    const int stride = gridDim.x * 256;
    for (int idx = blockIdx.x * 256 + threadIdx.x; idx < nquad; idx += stride) {
        float4 xv = ((const float4*)x)[idx];
        float xs[4] = {xv.x, xv.y, xv.z, xv.w};
        uint32_t w[4];
        #pragma unroll
        for (int e = 0; e < 4; ++e) {
            float xc = fminf(fmaxf(xs[e], -CLAMPV), CLAMPV);
            float ex = __expf(2.f * xc);
            float t  = (ex - 1.f) * __builtin_amdgcn_rcpf(ex + 1.f);  // tanh
            float t2 = fmaf(2.f * t, t,  -1.f);    // |T_d| <= 1 exactly
            float t3 = fmaf(2.f * t, t2, -t);
            float t4 = fmaf(2.f * t, t3, -t2);
            w[e] = pack4(t * 127.f, t2 * 127.f, t3 * 127.f, t4 * 127.f);
        }
        uint4 o4; o4.x = w[0]; o4.y = w[1]; o4.z = w[2]; o4.w = w[3];
        ((uint4*)A)[idx] = o4;
    }
}

// ---------------------------------------------------------------------------
// gemm: 256x256 tile, BKE=128 i8, 8 waves (2Mx4N), 8-phase, counted vmcnt.
// Byte-geometry identical to the verified bf16 version (128 B/row tiles,
// same XOR swizzle both sides, same staging parts/order, same vmcnt ledger).
// MFMA: i32_16x16x64_i8, 2x ops per instruction vs bf16.
// ---------------------------------------------------------------------------
__global__ __launch_bounds__(512, 2)
void gemm_bt(const i8* __restrict__ A, const i8* __restrict__ B,
             const float* __restrict__ bias, const float* __restrict__ scale,
             float* __restrict__ C, int row0)
{
    __shared__ i8 lds[2][2][256][BKE];   // 131072 B

    const int tid  = threadIdx.x;
    const int lane = tid & 63;
    const int wid  = tid >> 6;
    const int wm   = wid >> 2;      // 0..1
    const int wn   = wid & 3;       // 0..3

    // XCD-aware swizzle (gridDim.x % 8 == 0)
    const int bid = blockIdx.x;
    const int cpx = gridDim.x >> 3;
    const int swz = (bid & 7) * cpx + (bid >> 3);
    const int bn = swz & 7;
    const int bm = swz >> 3;

    const char* gA = (const char*)A + (size_t)bm * 256 * ROWB;
    const char* gB = (const char*)B + (size_t)bn * 256 * ROWB;

    // ---- staging maps (2 glds per part per thread), unchanged bytes ----
    const int c  = tid & 7;
    const int rA = tid >> 3;
    const int rB = rA & 31;
    const int hb = tid >> 8;
    const int rA0_0 = rA,           rA0_1 = 128 + rA;            // p0
    const int rA1_0 = 64 + rA,      rA1_1 = 192 + rA;            // p3
    const int rB0_0 = hb*64 + rB,   rB0_1 = 128 + hb*64 + rB;    // p1
    const int rB1_0 = rB0_0 + 32,   rB1_1 = rB0_1 + 32;          // p2
#define SOFF(r) ((r) * ROWB + (((c ^ ((r) & 7))) << 4))
#define DOFF(r) ((r) * 128 + (c << 4))
    const int soA0_0 = SOFF(rA0_0), doA0_0 = DOFF(rA0_0);
    const int soA0_1 = SOFF(rA0_1), doA0_1 = DOFF(rA0_1);
    const int soA1_0 = SOFF(rA1_0), doA1_0 = DOFF(rA1_0);
    const int soA1_1 = SOFF(rA1_1), doA1_1 = DOFF(rA1_1);
    const int soB0_0 = SOFF(rB0_0), doB0_0 = DOFF(rB0_0);
    const int soB0_1 = SOFF(rB0_1), doB0_1 = DOFF(rB0_1);
    const int soB1_0 = SOFF(rB1_0), doB1_0 = DOFF(rB1_0);
    const int soB1_1 = SOFF(rB1_1), doB1_1 = DOFF(rB1_1);
#undef SOFF
#undef DOFF

    char* lbase = (char*)&lds[0][0][0][0];
    auto ST = [&](const char* gb, char* lb, int tile,
                  int so0, int do0, int so1, int do1) {
        const int kb = tile * 128;           // 128 B per K-step along the row
        gload_lds16(gb + kb + so0, lb + do0);
        gload_lds16(gb + kb + so1, lb + do1);
    };

    // ---- fragment-read addressing (identical byte offsets) ----
    const int aBase = (wm * 128 + (lane & 15)) * 128;
    const int bBase = (wn * 64  + (lane & 15)) * 128;
    const int sw  = (lane & 7) << 4;
    const int cb0 = ( (lane & 0x30)      ) ^ sw;
    const int cb1 = ( (lane & 0x30) + 64 ) ^ sw;

    i32x4 acc[8][4] = {};
    int4v aF[4][2], bE[2][2], bO[2][2];

    // ---- prologue: tile0 p0-p3, tile1 p0-p2 ----
    ST(gA, lbase,                 0, soA0_0, doA0_0, soA0_1, doA0_1);
    ST(gB, lbase + 32768,         0, soB0_0, doB0_0, soB0_1, doB0_1);
    ST(gB, lbase + 32768,         0, soB1_0, doB1_0, soB1_1, doB1_1);
    ST(gA, lbase,                 0, soA1_0, doA1_0, soA1_1, doA1_1);
    ST(gA, lbase + 65536,         1, soA0_0, doA0_0, soA0_1, doA0_1);
    ST(gB, lbase + 65536 + 32768, 1, soB0_0, doB0_0, soB0_1, doB0_1);
    ST(gB, lbase + 65536 + 32768, 1, soB1_0, doB1_0, soB1_1, doB1_1);
    asm volatile("s_waitcnt vmcnt(6)" ::: "memory");
    __builtin_amdgcn_s_barrier();

#define PHASE_SYNC()                                          \
    __builtin_amdgcn_s_barrier();                             \
    asm volatile("s_waitcnt lgkmcnt(0)" ::: "memory");        \
    __builtin_amdgcn_sched_barrier(0)

    for (int t = 0; t < NT; ++t) {
        char* sA  = lbase + (t & 1) * 65536;
        char* sB  = sA + 32768;
        char* sAo = lbase + ((t + 1) & 1) * 65536;

        // ---------------- P1: quad (mh0, nh0) ----------------
        #pragma unroll
        for (int m = 0; m < 4; ++m) {
            aF[m][0] = *(const int4v*)(sA + aBase + m * 2048 + cb0);
            aF[m][1] = *(const int4v*)(sA + aBase + m * 2048 + cb1);
        }
        #pragma unroll
        for (int n = 0; n < 2; ++n) {
            bE[n][0] = *(const int4v*)(sB + bBase + n * 2048 + cb0);
            bE[n][1] = *(const int4v*)(sB + bBase + n * 2048 + cb1);
        }
        if (t + 1 < NT) ST(gA, sAo, t + 1, soA1_0, doA1_0, soA1_1, doA1_1);
        PHASE_SYNC();
        __builtin_amdgcn_s_setprio(1);
        #pragma unroll
        for (int ks = 0; ks < 2; ++ks)
            #pragma unroll
            for (int m = 0; m < 4; ++m)
                #pragma unroll
                for (int n = 0; n < 2; ++n)
                    acc[m][n] = __builtin_amdgcn_mfma_i32_16x16x64_i8(
                        aF[m][ks], bE[n][ks], acc[m][n], 0, 0, 0);
        __builtin_amdgcn_s_setprio(0);
        __builtin_amdgcn_s_barrier();

        // ---------------- P2: quad (mh0, nh1) ----------------
        #pragma unroll
        for (int n = 0; n < 2; ++n) {
            bO[n][0] = *(const int4v*)(sB + bBase + (n + 2) * 2048 + cb0);
            bO[n][1] = *(const int4v*)(sB + bBase + (n + 2) * 2048 + cb1);
        }
        if (t + 2 < NT) ST(gA, sA, t + 2, soA0_0, doA0_0, soA0_1, doA0_1);
        PHASE_SYNC();
        __builtin_amdgcn_s_setprio(1);
        #pragma unroll
        for (int ks = 0; ks < 2; ++ks)
            #pragma unroll
            for (int m = 0; m < 4; ++m)
                #pragma unroll
                for (int n = 0; n < 2; ++n)
                    acc[m][n + 2] = __builtin_amdgcn_mfma_i32_16x16x64_i8(
                        aF[m][ks], bO[n][ks], acc[m][n + 2], 0, 0, 0);
        __builtin_amdgcn_s_setprio(0);
        __builtin_amdgcn_s_barrier();

        // ---------------- P3: quad (mh1, nh1) ----------------
        #pragma unroll
        for (int m = 0; m < 4; ++m) {
            aF[m][0] = *(const int4v*)(sA + aBase + 8192 + m * 2048 + cb0);
            aF[m][1] = *(const int4v*)(sA + aBase + 8192 + m * 2048 + cb1);
        }
        if (t + 2 < NT) ST(gB, sB, t + 2, soB0_0, doB0_0, soB0_1, doB0_1);
        PHASE_SYNC();
        __builtin_amdgcn_s_setprio(1);
        #pragma unroll
        for (int ks = 0; ks < 2; ++ks)
            #pragma unroll
            for (int m = 0; m < 4; ++m)
                #pragma unroll
                for (int n = 0; n < 2; ++n)
                    acc[m + 4][n + 2] = __builtin_amdgcn_mfma_i32_16x16x64_i8(
                        aF[m][ks], bO[n][ks], acc[m + 4][n + 2], 0, 0, 0);
        __builtin_amdgcn_s_setprio(0);
        __builtin_amdgcn_s_barrier();

        // ---------------- P4: quad (mh1, nh0) ----------------
        if (t + 2 < NT) ST(gB, sB, t + 2, soB1_0, doB1_0, soB1_1, doB1_1);
        PHASE_SYNC();
        __builtin_amdgcn_s_setprio(1);
        #pragma unroll
        for (int ks = 0; ks < 2; ++ks)
            #pragma unroll
            for (int m = 0; m < 4; ++m)
                #pragma unroll
                for (int n = 0; n < 2; ++n)
                    acc[m + 4][n] = __builtin_amdgcn_mfma_i32_16x16x64_i8(
                        aF[m][ks], bE[n][ks], acc[m + 4][n], 0, 0, 0);
        __builtin_amdgcn_s_setprio(0);
        if (t < NT - 2)       { asm volatile("s_waitcnt vmcnt(6)" ::: "memory"); }
        else if (t == NT - 2) { asm volatile("s_waitcnt vmcnt(0)" ::: "memory"); }
        __builtin_amdgcn_s_barrier();
    }
#undef PHASE_SYNC

    // ---- epilogue: dequant (sA=1/127, sB[col]), + bias, clip, store fp32 ----
    float bia[4], fsc[4];
    #pragma unroll
    for (int n = 0; n < 4; ++n) {
        const int col = bn * 256 + wn * 64 + n * 16 + (lane & 15);
        bia[n] = bias[col];
        fsc[n] = scale[col] * (1.f / 127.f);
    }

    #pragma unroll
    for (int m = 0; m < 8; ++m) {
        const int rb = row0 + bm * 256 + wm * 128 + m * 16 + ((lane >> 4) << 2);
        #pragma unroll
        for (int n = 0; n < 4; ++n) {
            const int col = bn * 256 + wn * 64 + n * 16 + (lane & 15);
            #pragma unroll
            for (int r = 0; r < 4; ++r) {
                float v = fmaf((float)acc[m][n][r], fsc[n], bia[n]);
                v = fminf(fmaxf(v, -CLAMPV), CLAMPV);
                C[(size_t)(rb + r) * ODIM + col] = v;
            }
        }
    }
}

// ---------------------------------------------------------------------------
extern "C" void kernel_launch(void* const* d_in, const int* in_sizes, int n_in,
                              void* d_out, int out_size, void* d_ws, size_t ws_size,
                              hipStream_t stream)
{
    const float* x      = (const float*)d_in[0];
    const float* coeffs = (const float*)d_in[1];
    float* out = (float*)d_out;

    char* ws = (char*)d_ws;
    const size_t bBytes    = (size_t)ODIM * KTOT;       // 16.8 MB (i8)
    const size_t biasBytes = ODIM * sizeof(float);      // 8 KB
    const size_t sclBytes  = ODIM * sizeof(float);      // 8 KB
    uint32_t* Bp   = (uint32_t*)ws;
    float*    bias = (float*)(ws + bBytes);
    float*    scl  = (float*)(ws + bBytes + biasBytes);
    i8*       Ap   = (i8*)(ws + bBytes + biasBytes + sclBytes);

    size_t avail = (ws_size > bBytes + biasBytes + sclBytes)
                 ? ws_size - bBytes - biasBytes - sclBytes : 0;
    int chunk = NROWS;
    while (chunk > 256 && (size_t)chunk * KTOT > avail) chunk >>= 1;

    pack_coeffs<<<ODIM, 256, 0, stream>>>(coeffs, Bp, bias, scl);

    for (int r0 = 0; r0 < NROWS; r0 += chunk) {
        cheb_pack<<<2048, 256, 0, stream>>>(x + (size_t)r0 * IDIM,
                                            (uint32_t*)(Ap + (size_t)0), chunk * IDIM / 4);
        gemm_bt<<<(chunk / 256) * 8, 512, 0, stream>>>(
            Ap, (const i8*)Bp, bias, scl, out, r0);
    }
}

// Round 5
// 514.342 us; speedup vs baseline: 1.9100x; 1.0018x over previous
//
#include <hip/hip_runtime.h>
#include <hip/hip_bf16.h>
#include <stdint.h>

#define CLAMPV 10.0f

typedef signed char i8;
typedef __attribute__((ext_vector_type(4))) int   i32x4;
typedef __attribute__((ext_vector_type(4))) int   int4v;

#define NROWS 16384
#define IDIM  2048
#define ODIM  2048
#define KTOT  8192            // IDIM*4 (T1..T4 as i8; T0 folded into bias)
#define BKE   128             // i8 elems per K-step = 128 B/row
#define NT    (KTOT / BKE)    // 64 K-tiles
#define ROWB  KTOT            // bytes per matrix row (i8)

#define CHEB_BLKS 3072        // cheb-path blocks in merged prep kernel

__device__ __forceinline__ void gload_lds16(const void* g, void* l) {
    __builtin_amdgcn_global_load_lds(
        (const __attribute__((address_space(1))) void*)g,
        (__attribute__((address_space(3))) void*)l, 16, 0, 0);
}

__device__ __forceinline__ uint32_t pack4(float a, float b, float c, float d) {
    int q0 = (int)rintf(a), q1 = (int)rintf(b), q2 = (int)rintf(c), q3 = (int)rintf(d);
    return (uint32_t)(uint8_t)q0 | ((uint32_t)(uint8_t)q1 << 8) |
           ((uint32_t)(uint8_t)q2 << 16) | ((uint32_t)(uint8_t)q3 << 24);
}

// ---------------------------------------------------------------------------
// prep: merged prepass. Groups of 5 blocks: 2 pack-coeff rows + 3 cheb blocks,
// interleaved so both kinds co-run from t=0 (independent work, time = max not sum).
// pack path: two passes over the row (pass2 hits L2; row = 40 KB), 64 B LDS only.
// cheb path: grid-stride; 16B in -> tanh -> T1..T4 -> i8 -> 16B out.
// ---------------------------------------------------------------------------
__global__ __launch_bounds__(256)
void prep(const float* __restrict__ coeffs, const float* __restrict__ x,
          uint32_t* __restrict__ B, float* __restrict__ bias,
          float* __restrict__ scale, uint32_t* __restrict__ A, int nquad)
{
    const int tid = threadIdx.x;
    const int grp = blockIdx.x / 5, sub = blockIdx.x % 5;

    if (sub < 2) {
        // ---- pack_coeffs path: one row o per block ----
        __shared__ float red[16];
        const int o = grp * 2 + sub;
        const float* rp = coeffs + (size_t)o * IDIM * 5;

        float s0 = 0.f, mx = 0.f;
        for (int i = tid; i < IDIM; i += 256) {
            const float* c = rp + i * 5;
            s0 += c[0];
            mx = fmaxf(mx, fmaxf(fmaxf(fabsf(c[1]), fabsf(c[2])),
                                 fmaxf(fabsf(c[3]), fabsf(c[4]))));
        }
        #pragma unroll
        for (int off = 32; off; off >>= 1) {
            s0 += __shfl_down(s0, off);
            mx = fmaxf(mx, __shfl_down(mx, off));
        }
        if ((tid & 63) == 0) { red[tid >> 6] = s0; red[8 + (tid >> 6)] = mx; }
        __syncthreads();
        const float m  = fmaxf(fmaxf(red[8], red[9]), fmaxf(red[10], red[11]));
        const float rs = 127.f / fmaxf(m, 1e-30f);
        if (tid == 0) {
            bias[o]  = red[0] + red[1] + red[2] + red[3];
            scale[o] = m * (1.f / 127.f);
        }
        for (int i = tid; i < IDIM; i += 256) {
            const float* c = rp + i * 5;           // L2-hot re-read (40 KB row)
            B[(size_t)o * IDIM + i] =
                pack4(c[1] * rs, c[2] * rs, c[3] * rs, c[4] * rs);
        }
    } else {
        // ---- cheb path ----
        const int cb = grp * 3 + (sub - 2);        // 0..CHEB_BLKS-1
        const int stride = CHEB_BLKS * 256;
        for (int idx = cb * 256 + tid; idx < nquad; idx += stride) {
            float4 xv = ((const float4*)x)[idx];
            float xs[4] = {xv.x, xv.y, xv.z, xv.w};
            uint32_t w[4];
            #pragma unroll
            for (int e = 0; e < 4; ++e) {
                float xc = fminf(fmaxf(xs[e], -CLAMPV), CLAMPV);
                float ex = __expf(2.f * xc);
                float t  = (ex - 1.f) * __builtin_amdgcn_rcpf(ex + 1.f);
                float t2 = fmaf(2.f * t, t,  -1.f);    // |T_d| <= 1 exactly
                float t3 = fmaf(2.f * t, t2, -t);
                float t4 = fmaf(2.f * t, t3, -t2);
                w[e] = pack4(t * 127.f, t2 * 127.f, t3 * 127.f, t4 * 127.f);
            }
            uint4 o4; o4.x = w[0]; o4.y = w[1]; o4.z = w[2]; o4.w = w[3];
            ((uint4*)A)[idx] = o4;
        }
    }
}

// ---------------------------------------------------------------------------
// cheb-only fallback (used if workspace forces row-chunking)
// ---------------------------------------------------------------------------
__global__ __launch_bounds__(256)
void cheb_pack(const float* __restrict__ x, uint32_t* __restrict__ A, int nquad)
{
    const int stride = gridDim.x * 256;
    for (int idx = blockIdx.x * 256 + threadIdx.x; idx < nquad; idx += stride) {
        float4 xv = ((const float4*)x)[idx];
        float xs[4] = {xv.x, xv.y, xv.z, xv.w};
        uint32_t w[4];
        #pragma unroll
        for (int e = 0; e < 4; ++e) {
            float xc = fminf(fmaxf(xs[e], -CLAMPV), CLAMPV);
            float ex = __expf(2.f * xc);
            float t  = (ex - 1.f) * __builtin_amdgcn_rcpf(ex + 1.f);
            float t2 = fmaf(2.f * t, t,  -1.f);
            float t3 = fmaf(2.f * t, t2, -t);
            float t4 = fmaf(2.f * t, t3, -t2);
            w[e] = pack4(t * 127.f, t2 * 127.f, t3 * 127.f, t4 * 127.f);
        }
        uint4 o4; o4.x = w[0]; o4.y = w[1]; o4.z = w[2]; o4.w = w[3];
        ((uint4*)A)[idx] = o4;
    }
}

__global__ __launch_bounds__(256)
void pack_coeffs(const float* __restrict__ coeffs, uint32_t* __restrict__ B,
                 float* __restrict__ bias, float* __restrict__ scale)
{
    __shared__ float red[16];
    const int o = blockIdx.x;
    const int tid = threadIdx.x;
    const float* rp = coeffs + (size_t)o * IDIM * 5;
    float s0 = 0.f, mx = 0.f;
    for (int i = tid; i < IDIM; i += 256) {
        const float* c = rp + i * 5;
        s0 += c[0];
        mx = fmaxf(mx, fmaxf(fmaxf(fabsf(c[1]), fabsf(c[2])),
                             fmaxf(fabsf(c[3]), fabsf(c[4]))));
    }
    #pragma unroll
    for (int off = 32; off; off >>= 1) {
        s0 += __shfl_down(s0, off);
        mx = fmaxf(mx, __shfl_down(mx, off));
    }
    if ((tid & 63) == 0) { red[tid >> 6] = s0; red[8 + (tid >> 6)] = mx; }
    __syncthreads();
    const float m  = fmaxf(fmaxf(red[8], red[9]), fmaxf(red[10], red[11]));
    const float rs = 127.f / fmaxf(m, 1e-30f);
    if (tid == 0) {
        bias[o]  = red[0] + red[1] + red[2] + red[3];
        scale[o] = m * (1.f / 127.f);
    }
    for (int i = tid; i < IDIM; i += 256) {
        const float* c = rp + i * 5;
        B[(size_t)o * IDIM + i] = pack4(c[1] * rs, c[2] * rs, c[3] * rs, c[4] * rs);
    }
}

// ---------------------------------------------------------------------------
// gemm: byte-identical schedule to R4 (verified): 256x256 tile, BKE=128 i8,
// 8 waves, 8-phase, counted vmcnt(6), XOR swizzle both sides, i8 MFMA.
// ---------------------------------------------------------------------------
__global__ __launch_bounds__(512, 2)
void gemm_bt(const i8* __restrict__ A, const i8* __restrict__ B,
             const float* __restrict__ bias, const float* __restrict__ scale,
             float* __restrict__ C, int row0)
{
    __shared__ i8 lds[2][2][256][BKE];   // 131072 B

    const int tid  = threadIdx.x;
    const int lane = tid & 63;
    const int wid  = tid >> 6;
    const int wm   = wid >> 2;
    const int wn   = wid & 3;

    const int bid = blockIdx.x;
    const int cpx = gridDim.x >> 3;
    const int swz = (bid & 7) * cpx + (bid >> 3);
    const int bn = swz & 7;
    const int bm = swz >> 3;

    const char* gA = (const char*)A + (size_t)bm * 256 * ROWB;
    const char* gB = (const char*)B + (size_t)bn * 256 * ROWB;

    const int c  = tid & 7;
    const int rA = tid >> 3;
    const int rB = rA & 31;
    const int hb = tid >> 8;
    const int rA0_0 = rA,           rA0_1 = 128 + rA;            // p0
    const int rA1_0 = 64 + rA,      rA1_1 = 192 + rA;            // p3
    const int rB0_0 = hb*64 + rB,   rB0_1 = 128 + hb*64 + rB;    // p1
    const int rB1_0 = rB0_0 + 32,   rB1_1 = rB0_1 + 32;          // p2
#define SOFF(r) ((r) * ROWB + (((c ^ ((r) & 7))) << 4))
#define DOFF(r) ((r) * 128 + (c << 4))
    const int soA0_0 = SOFF(rA0_0), doA0_0 = DOFF(rA0_0);
    const int soA0_1 = SOFF(rA0_1), doA0_1 = DOFF(rA0_1);
    const int soA1_0 = SOFF(rA1_0), doA1_0 = DOFF(rA1_0);
    const int soA1_1 = SOFF(rA1_1), doA1_1 = DOFF(rA1_1);
    const int soB0_0 = SOFF(rB0_0), doB0_0 = DOFF(rB0_0);
    const int soB0_1 = SOFF(rB0_1), doB0_1 = DOFF(rB0_1);
    const int soB1_0 = SOFF(rB1_0), doB1_0 = DOFF(rB1_0);
    const int soB1_1 = SOFF(rB1_1), doB1_1 = DOFF(rB1_1);
#undef SOFF
#undef DOFF

    char* lbase = (char*)&lds[0][0][0][0];
    auto ST = [&](const char* gb, char* lb, int tile,
                  int so0, int do0, int so1, int do1) {
        const int kb = tile * 128;
        gload_lds16(gb + kb + so0, lb + do0);
        gload_lds16(gb + kb + so1, lb + do1);
    };

    const int aBase = (wm * 128 + (lane & 15)) * 128;
    const int bBase = (wn * 64  + (lane & 15)) * 128;
    const int sw  = (lane & 7) << 4;
    const int cb0 = ( (lane & 0x30)      ) ^ sw;
    const int cb1 = ( (lane & 0x30) + 64 ) ^ sw;

    i32x4 acc[8][4] = {};
    int4v aF[4][2], bE[2][2], bO[2][2];

    ST(gA, lbase,                 0, soA0_0, doA0_0, soA0_1, doA0_1);
    ST(gB, lbase + 32768,         0, soB0_0, doB0_0, soB0_1, doB0_1);
    ST(gB, lbase + 32768,         0, soB1_0, doB1_0, soB1_1, doB1_1);
    ST(gA, lbase,                 0, soA1_0, doA1_0, soA1_1, doA1_1);
    ST(gA, lbase + 65536,         1, soA0_0, doA0_0, soA0_1, doA0_1);
    ST(gB, lbase + 65536 + 32768, 1, soB0_0, doB0_0, soB0_1, doB0_1);
    ST(gB, lbase + 65536 + 32768, 1, soB1_0, doB1_0, soB1_1, doB1_1);
    asm volatile("s_waitcnt vmcnt(6)" ::: "memory");
    __builtin_amdgcn_s_barrier();

#define PHASE_SYNC()                                          \
    __builtin_amdgcn_s_barrier();                             \
    asm volatile("s_waitcnt lgkmcnt(0)" ::: "memory");        \
    __builtin_amdgcn_sched_barrier(0)

    for (int t = 0; t < NT; ++t) {
        char* sA  = lbase + (t & 1) * 65536;
        char* sB  = sA + 32768;
        char* sAo = lbase + ((t + 1) & 1) * 65536;

        // ---------------- P1: quad (mh0, nh0) ----------------
        #pragma unroll
        for (int m = 0; m < 4; ++m) {
            aF[m][0] = *(const int4v*)(sA + aBase + m * 2048 + cb0);
            aF[m][1] = *(const int4v*)(sA + aBase + m * 2048 + cb1);
        }
        #pragma unroll
        for (int n = 0; n < 2; ++n) {
            bE[n][0] = *(const int4v*)(sB + bBase + n * 2048 + cb0);
            bE[n][1] = *(const int4v*)(sB + bBase + n * 2048 + cb1);
        }
        if (t + 1 < NT) ST(gA, sAo, t + 1, soA1_0, doA1_0, soA1_1, doA1_1);
        PHASE_SYNC();
        __builtin_amdgcn_s_setprio(1);
        #pragma unroll
        for (int ks = 0; ks < 2; ++ks)
            #pragma unroll
            for (int m = 0; m < 4; ++m)
                #pragma unroll
                for (int n = 0; n < 2; ++n)
                    acc[m][n] = __builtin_amdgcn_mfma_i32_16x16x64_i8(
                        aF[m][ks], bE[n][ks], acc[m][n], 0, 0, 0);
        __builtin_amdgcn_s_setprio(0);
        __builtin_amdgcn_s_barrier();

        // ---------------- P2: quad (mh0, nh1) ----------------
        #pragma unroll
        for (int n = 0; n < 2; ++n) {
            bO[n][0] = *(const int4v*)(sB + bBase + (n + 2) * 2048 + cb0);
            bO[n][1] = *(const int4v*)(sB + bBase + (n + 2) * 2048 + cb1);
        }
        if (t + 2 < NT) ST(gA, sA, t + 2, soA0_0, doA0_0, soA0_1, doA0_1);
        PHASE_SYNC();
        __builtin_amdgcn_s_setprio(1);
        #pragma unroll
        for (int ks = 0; ks < 2; ++ks)
            #pragma unroll
            for (int m = 0; m < 4; ++m)
                #pragma unroll
                for (int n = 0; n < 2; ++n)
                    acc[m][n + 2] = __builtin_amdgcn_mfma_i32_16x16x64_i8(
                        aF[m][ks], bO[n][ks], acc[m][n + 2], 0, 0, 0);
        __builtin_amdgcn_s_setprio(0);
        __builtin_amdgcn_s_barrier();

        // ---------------- P3: quad (mh1, nh1) ----------------
        #pragma unroll
        for (int m = 0; m < 4; ++m) {
            aF[m][0] = *(const int4v*)(sA + aBase + 8192 + m * 2048 + cb0);
            aF[m][1] = *(const int4v*)(sA + aBase + 8192 + m * 2048 + cb1);
        }
        if (t + 2 < NT) ST(gB, sB, t + 2, soB0_0, doB0_0, soB0_1, doB0_1);
        PHASE_SYNC();
        __builtin_amdgcn_s_setprio(1);
        #pragma unroll
        for (int ks = 0; ks < 2; ++ks)
            #pragma unroll
            for (int m = 0; m < 4; ++m)
                #pragma unroll
                for (int n = 0; n < 2; ++n)
                    acc[m + 4][n + 2] = __builtin_amdgcn_mfma_i32_16x16x64_i8(
                        aF[m][ks], bO[n][ks], acc[m + 4][n + 2], 0, 0, 0);
        __builtin_amdgcn_s_setprio(0);
        __builtin_amdgcn_s_barrier();

        // ---------------- P4: quad (mh1, nh0) ----------------
        if (t + 2 < NT) ST(gB, sB, t + 2, soB1_0, doB1_0, soB1_1, doB1_1);
        PHASE_SYNC();
        __builtin_amdgcn_s_setprio(1);
        #pragma unroll
        for (int ks = 0; ks < 2; ++ks)
            #pragma unroll
            for (int m = 0; m < 4; ++m)
                #pragma unroll
                for (int n = 0; n < 2; ++n)
                    acc[m + 4][n] = __builtin_amdgcn_mfma_i32_16x16x64_i8(
                        aF[m][ks], bE[n][ks], acc[m + 4][n], 0, 0, 0);
        __builtin_amdgcn_s_setprio(0);
        if (t < NT - 2)       { asm volatile("s_waitcnt vmcnt(6)" ::: "memory"); }
        else if (t == NT - 2) { asm volatile("s_waitcnt vmcnt(0)" ::: "memory"); }
        __builtin_amdgcn_s_barrier();
    }
#undef PHASE_SYNC

    float bia[4], fsc[4];
    #pragma unroll
    for (int n = 0; n < 4; ++n) {
        const int col = bn * 256 + wn * 64 + n * 16 + (lane & 15);
        bia[n] = bias[col];
        fsc[n] = scale[col] * (1.f / 127.f);
    }

    #pragma unroll
    for (int m = 0; m < 8; ++m) {
        const int rb = row0 + bm * 256 + wm * 128 + m * 16 + ((lane >> 4) << 2);
        #pragma unroll
        for (int n = 0; n < 4; ++n) {
            const int col = bn * 256 + wn * 64 + n * 16 + (lane & 15);
            #pragma unroll
            for (int r = 0; r < 4; ++r) {
                float v = fmaf((float)acc[m][n][r], fsc[n], bia[n]);
                v = fminf(fmaxf(v, -CLAMPV), CLAMPV);
                C[(size_t)(rb + r) * ODIM + col] = v;
            }
        }
    }
}

// ---------------------------------------------------------------------------
extern "C" void kernel_launch(void* const* d_in, const int* in_sizes, int n_in,
                              void* d_out, int out_size, void* d_ws, size_t ws_size,
                              hipStream_t stream)
{
    const float* x      = (const float*)d_in[0];
    const float* coeffs = (const float*)d_in[1];
    float* out = (float*)d_out;

    char* ws = (char*)d_ws;
    const size_t bBytes    = (size_t)ODIM * KTOT;       // 16.8 MB (i8)
    const size_t biasBytes = ODIM * sizeof(float);
    const size_t sclBytes  = ODIM * sizeof(float);
    uint32_t* Bp   = (uint32_t*)ws;
    float*    bias = (float*)(ws + bBytes);
    float*    scl  = (float*)(ws + bBytes + biasBytes);
    i8*       Ap   = (i8*)(ws + bBytes + biasBytes + sclBytes);

    size_t avail = (ws_size > bBytes + biasBytes + sclBytes)
                 ? ws_size - bBytes - biasBytes - sclBytes : 0;
    int chunk = NROWS;
    while (chunk > 256 && (size_t)chunk * KTOT > avail) chunk >>= 1;

    if (chunk == NROWS) {
        // fast path: single merged prepass (pack ∥ cheb), then one gemm
        prep<<<2048 / 2 * 5, 256, 0, stream>>>(coeffs, x, Bp, bias, scl,
                                               (uint32_t*)Ap,
                                               NROWS * IDIM / 4);
        gemm_bt<<<(NROWS / 256) * 8, 512, 0, stream>>>(
            Ap, (const i8*)Bp, bias, scl, out, 0);
    } else {
        pack_coeffs<<<ODIM, 256, 0, stream>>>(coeffs, Bp, bias, scl);
        for (int r0 = 0; r0 < NROWS; r0 += chunk) {
            cheb_pack<<<2048, 256, 0, stream>>>(x + (size_t)r0 * IDIM,
                                                (uint32_t*)Ap, chunk * IDIM / 4);
            gemm_bt<<<(chunk / 256) * 8, 512, 0, stream>>>(
                Ap, (const i8*)Bp, bias, scl, out, r0);
        }
    }
}